// Round 3
// 308.811 us; speedup vs baseline: 1.0152x; 1.0152x over previous
//
#include <hip/hip_runtime.h>
#include <hip/hip_bf16.h>
#include <stdint.h>

// LSTM cell, fp32 I/O, GEMM via bf16 MFMA.
//   gates[b, 4H] = [x|h] @ W_stacked^T + b ; per-element LSTM combine, fp32 out.
// B=8192, I=H=1024, C=2048.
//
// Round 8 (= round 6 kernel; rounds 6-7 never ran: GPUAcquisitionTimeout):
// 256x256x64 8-phase pipelined GEMM (T2+T3+T4+T5 per learn_hip m201):
//  - 512 threads (8 waves, 2M x 4N), per-wave 128x64 output, acc[8][4].
//  - LDS 128 KB: 2 buffers x (A 256x64 + B 256x64) bf16, chunk-XOR swizzle
//    (same swizzle as round 5 -- measured 0 bank conflicts).
//  - Per K-tile 4 phases, each: ds_read frag subtile || stage ONE half-tile
//    (2x global_load_lds dwordx4) -> s_barrier -> lgkmcnt(0) -> setprio(1)
//    -> 16 MFMA -> setprio(0) -> s_barrier.  vmcnt(6) ONCE per K-tile
//    (3 half-tiles in flight across barriers; never drained to 0 in loop).
//  - Ledger: steady state ends each tile at 14 outstanding; vmcnt(6) retires
//    exactly tile u+1's 8 loads -> data lands a full K-tile before first read.
//  - Gate-interleaved B rows: wave wc's 4 j-frags = 4 gates at same 16 h-cols
//    -> in-register LSTM epilogue unchanged.
//  - cvt: grid-stride, 8 elems/thread, bf16x8 (16B) stores.

typedef __bf16 bf16x8 __attribute__((ext_vector_type(8)));
typedef __bf16 bf16x4 __attribute__((ext_vector_type(4)));
typedef float f32x4 __attribute__((ext_vector_type(4)));

#define B_DIM 8192
#define H_DIM 1024
#define C_DIM 2048

#define XH_ELEMS (B_DIM * H_DIM)               // 8388608
#define W_ELEMS  (H_DIM * C_DIM)               // 2097152
#define CVT_TOTAL (2 * XH_ELEMS + 4 * W_ELEMS) // 25165824 floats
#define WS_NEEDED ((size_t)CVT_TOTAL * 2)      // bytes of bf16

__device__ __forceinline__ void async_cp16(void* lds_dst, const void* g_src) {
    __builtin_amdgcn_global_load_lds(
        (const __attribute__((address_space(1))) void*)g_src,
        (__attribute__((address_space(3))) void*)lds_dst,
        16, 0, 0);
}

// ---------------- fp32 -> bf16 bulk convert (pass 1) ----------------
__global__ __launch_bounds__(256)
void cvt_kernel(const float* __restrict__ x, const float* __restrict__ h,
                const float* __restrict__ wi, const float* __restrict__ wf,
                const float* __restrict__ wo, const float* __restrict__ wg,
                __hip_bfloat16* __restrict__ dst)
{
    const size_t stride = (size_t)gridDim.x * 256;
    for (size_t t = (size_t)blockIdx.x * 256 + threadIdx.x;
         t < (size_t)(CVT_TOTAL / 8); t += stride) {
        const size_t base = t * 8;
        const float* src;
        size_t off;
        if (base < (size_t)XH_ELEMS)            { src = x; off = base; }
        else if (base < (size_t)2 * XH_ELEMS)   { src = h; off = base - XH_ELEMS; }
        else {
            const size_t wb = base - (size_t)2 * XH_ELEMS;
            const int g = (int)(wb >> 21);          // W_ELEMS = 2^21
            off = wb & (size_t)(W_ELEMS - 1);
            src = (g == 0) ? wi : (g == 1) ? wf : (g == 2) ? wo : wg;
        }
        const f32x4 v0 = *(const f32x4*)(src + off);
        const f32x4 v1 = *(const f32x4*)(src + off + 4);
        __hip_bfloat16 tmp[8];
        tmp[0] = __float2bfloat16(v0[0]); tmp[1] = __float2bfloat16(v0[1]);
        tmp[2] = __float2bfloat16(v0[2]); tmp[3] = __float2bfloat16(v0[3]);
        tmp[4] = __float2bfloat16(v1[0]); tmp[5] = __float2bfloat16(v1[1]);
        tmp[6] = __float2bfloat16(v1[2]); tmp[7] = __float2bfloat16(v1[3]);
        *(bf16x8*)(dst + base) = *(const bf16x8*)tmp;
    }
}

// ---------------- 256x256 8-phase GEMM + LSTM epilogue ----------------
__global__ __launch_bounds__(512, 2)
void lstm_gemm_bf16(const __hip_bfloat16* __restrict__ xb,
                    const __hip_bfloat16* __restrict__ hb,
                    const __hip_bfloat16* __restrict__ Wb,   // [4][H][C]
                    const float* __restrict__ c,
                    const float* __restrict__ pbi, const float* __restrict__ pbf,
                    const float* __restrict__ pbo, const float* __restrict__ pbg,
                    float* __restrict__ out)
{
    // [buf][A=0/B=1][row 0..255][col 0..63] bf16 = 128 KB
    __shared__ __hip_bfloat16 lds[2][2][256][64];
    char* const ldsBase = (char*)&lds[0][0][0][0];

    const int tid  = threadIdx.x;
    const int lane = tid & 63;
    const int wave = tid >> 6;        // 0..7
    const int wr   = wave >> 2;       // 0..1 (M)
    const int wc   = wave & 3;        // 0..3 (N)
    const int quad = lane >> 4;
    const int l16  = lane & 15;

    // XCD-aware swizzle: 512 blocks -> 64-block contiguous chunk per XCD.
    const int bid = (int)blockIdx.x;
    const int swz = (bid & 7) * 64 + (bid >> 3);
    const int m_base = (swz >> 4) * 256;   // 32 m-blocks
    const int n0     = (swz & 15) * 64;    // 16 n-blocks, 64 h-cols each

    // ---- staging offsets: per half-tile, li = a*512+tid in [0,1024) ----
    // row = li>>3 (within 128-row half), dst chunk = li&7,
    // SOURCE chunk = (li&7) ^ (row&7)  (XOR swizzle, involution).
    uint32_t aOff[2][2], bOff[2][2];       // [half][a], element offsets
#pragma unroll
    for (int a = 0; a < 2; ++a) {
        const int li  = a * 512 + tid;
        const int row = li >> 3;           // 0..127
        const int sch = ((li & 7) ^ (row & 7)) * 8;
#pragma unroll
        for (int hh = 0; hh < 2; ++hh) {
            aOff[hh][a] = (uint32_t)(m_base + hh * 128 + row) * H_DIM + (uint32_t)sch;
            // B rows: gate-interleaved so phase jh == B-half and
            // wave wc's j-frag rows map to (gate=j, hcol = n0 + wc*16 + l16).
            const int g   = (hh << 1) | ((row >> 4) & 1);
            const int hco = ((row >> 5) << 4) | (row & 15);
            bOff[hh][a] = (uint32_t)g * (uint32_t)W_ELEMS
                        + (uint32_t)(n0 + hco) * (uint32_t)C_DIM + (uint32_t)sch;
        }
    }
    const uint32_t dstT = (uint32_t)tid * 16u;

#define STAGE_A(pO, hh, srcp, kel) do {                                                        \
    async_cp16(ldsBase + (pO) + (hh) * 16384u + 0u    + dstT, (srcp) + aOff[hh][0] + (kel));   \
    async_cp16(ldsBase + (pO) + (hh) * 16384u + 8192u + dstT, (srcp) + aOff[hh][1] + (kel));   \
} while (0)
#define STAGE_B(pO, hh, kel) do {                                                              \
    async_cp16(ldsBase + (pO) + 32768u + (hh) * 16384u + 0u    + dstT, Wb + bOff[hh][0] + (kel)); \
    async_cp16(ldsBase + (pO) + 32768u + (hh) * 16384u + 8192u + dstT, Wb + bOff[hh][1] + (kel)); \
} while (0)

    // ---- fragment read bases (swizzled chunk = (s*4+quad)^(row&7), row&7 == l16&7) ----
    const uint32_t cb    = (uint32_t)((quad ^ (l16 & 7)) * 16);
    const uint32_t aBase = (uint32_t)(wr * 64 + l16) * 128u + cb;            // A region
    const uint32_t bBase = 32768u + (uint32_t)(wc * 32 + l16) * 128u + cb;   // B region

#define LDA(dstv, pO, ihh, ii, ss) \
    dstv = *(const bf16x8*)(ldsBase + (pO) + ((aBase + (ihh) * 16384u + (ii) * 2048u) ^ ((uint32_t)(ss) << 6)))
#define LDB(dstv, pO, jj, ss) \
    dstv = *(const bf16x8*)(ldsBase + (pO) + ((bBase + (((jj) >> 1)) * 16384u + ((jj) & 1) * 2048u) ^ ((uint32_t)(ss) << 6)))

    f32x4 acc[8][4];
#pragma unroll
    for (int i = 0; i < 8; ++i)
#pragma unroll
        for (int j = 0; j < 4; ++j)
            acc[i][j] = (f32x4){0.f, 0.f, 0.f, 0.f};

    // ---- prologue: tile0 {A0,B0,B1,A1}, tile1 {A0,B0,B1}; tile1's A1 comes
    //      from tile0's phase 1.  vmcnt(6) leaves the 3 newest halves in flight.
    STAGE_A(0u, 0, xb, 0u);
    STAGE_B(0u, 0, 0u);
    STAGE_B(0u, 1, 0u);
    STAGE_A(0u, 1, xb, 0u);
    STAGE_A(65536u, 0, xb, 64u);
    STAGE_B(65536u, 0, 64u);
    STAGE_B(65536u, 1, 64u);
    asm volatile("s_waitcnt vmcnt(6)" ::: "memory");
    __builtin_amdgcn_s_barrier();

    bf16x8 av[4][2], bv0[2][2], bv1[2][2];

    for (int u = 0; u < 32; ++u) {
        const uint32_t pO = (uint32_t)(u & 1) * 65536u;   // tile u's buffer
        const uint32_t qO = pO ^ 65536u;                  // tile u+1's buffer
        const __hip_bfloat16* aS1 = (u + 1 < 16) ? xb : hb;
        const uint32_t ak1 = (uint32_t)((u + 1) & 15) * 64u;
        const __hip_bfloat16* aS2 = (u + 2 < 16) ? xb : hb;
        const uint32_t ak2 = (uint32_t)((u + 2) & 15) * 64u;
        const uint32_t bk2 = (uint32_t)(u + 2) * 64u;

        // ---------- phase 1: quadrant A0 x B0 ; stage A1 of tile u+1 ----------
#pragma unroll
        for (int i = 0; i < 4; ++i) { LDA(av[i][0], pO, 0, i, 0); LDA(av[i][1], pO, 0, i, 1); }
#pragma unroll
        for (int j = 0; j < 2; ++j) { LDB(bv0[j][0], pO, j, 0); LDB(bv0[j][1], pO, j, 1); }
        if (u < 31) STAGE_A(qO, 1, aS1, ak1);
        __builtin_amdgcn_s_barrier();
        asm volatile("s_waitcnt lgkmcnt(0)" ::: "memory");
        __builtin_amdgcn_sched_barrier(0);
        __builtin_amdgcn_s_setprio(1);
#pragma unroll
        for (int i = 0; i < 4; ++i)
#pragma unroll
            for (int j = 0; j < 2; ++j) {
                acc[i][j] = __builtin_amdgcn_mfma_f32_16x16x32_bf16(av[i][0], bv0[j][0], acc[i][j], 0, 0, 0);
                acc[i][j] = __builtin_amdgcn_mfma_f32_16x16x32_bf16(av[i][1], bv0[j][1], acc[i][j], 0, 0, 0);
            }
        __builtin_amdgcn_s_setprio(0);
        __builtin_amdgcn_s_barrier();

        // ---------- phase 2: A0 x B1 ; stage A0 of tile u+2 (A0 region idle since P1) ----------
#pragma unroll
        for (int j = 0; j < 2; ++j) { LDB(bv1[j][0], pO, j + 2, 0); LDB(bv1[j][1], pO, j + 2, 1); }
        if (u < 30) STAGE_A(pO, 0, aS2, ak2);
        __builtin_amdgcn_s_barrier();
        asm volatile("s_waitcnt lgkmcnt(0)" ::: "memory");
        __builtin_amdgcn_sched_barrier(0);
        __builtin_amdgcn_s_setprio(1);
#pragma unroll
        for (int i = 0; i < 4; ++i)
#pragma unroll
            for (int j = 0; j < 2; ++j) {
                acc[i][j + 2] = __builtin_amdgcn_mfma_f32_16x16x32_bf16(av[i][0], bv1[j][0], acc[i][j + 2], 0, 0, 0);
                acc[i][j + 2] = __builtin_amdgcn_mfma_f32_16x16x32_bf16(av[i][1], bv1[j][1], acc[i][j + 2], 0, 0, 0);
            }
        __builtin_amdgcn_s_setprio(0);
        __builtin_amdgcn_s_barrier();

        // ---------- phase 3: A1 x B0 ; stage B0 of tile u+2 (B0 region idle since P1) ----------
#pragma unroll
        for (int i = 0; i < 4; ++i) { LDA(av[i][0], pO, 1, i, 0); LDA(av[i][1], pO, 1, i, 1); }
        if (u < 30) STAGE_B(pO, 0, bk2);
        __builtin_amdgcn_s_barrier();
        asm volatile("s_waitcnt lgkmcnt(0)" ::: "memory");
        __builtin_amdgcn_sched_barrier(0);
        __builtin_amdgcn_s_setprio(1);
#pragma unroll
        for (int i = 0; i < 4; ++i)
#pragma unroll
            for (int j = 0; j < 2; ++j) {
                acc[i + 4][j] = __builtin_amdgcn_mfma_f32_16x16x32_bf16(av[i][0], bv0[j][0], acc[i + 4][j], 0, 0, 0);
                acc[i + 4][j] = __builtin_amdgcn_mfma_f32_16x16x32_bf16(av[i][1], bv0[j][1], acc[i + 4][j], 0, 0, 0);
            }
        __builtin_amdgcn_s_setprio(0);
        __builtin_amdgcn_s_barrier();

        // ---------- phase 4: A1 x B1 ; stage B1 of tile u+2 (B1 region idle since P2) ----------
        if (u < 30) STAGE_B(pO, 1, bk2);
        __builtin_amdgcn_s_barrier();
        __builtin_amdgcn_s_setprio(1);
#pragma unroll
        for (int i = 0; i < 4; ++i)
#pragma unroll
            for (int j = 0; j < 2; ++j) {
                acc[i + 4][j + 2] = __builtin_amdgcn_mfma_f32_16x16x32_bf16(av[i][0], bv1[j][0], acc[i + 4][j + 2], 0, 0, 0);
                acc[i + 4][j + 2] = __builtin_amdgcn_mfma_f32_16x16x32_bf16(av[i][1], bv1[j][1], acc[i + 4][j + 2], 0, 0, 0);
            }
        __builtin_amdgcn_s_setprio(0);
        // Once-per-K-tile counted wait: tile u+1 fully landed, newest 3 halves
        // (tile u+2) stay in flight.  Epilogue tiles drain (u==30 -> 0).
        if (u < 30)       { asm volatile("s_waitcnt vmcnt(6)" ::: "memory"); }
        else if (u == 30) { asm volatile("s_waitcnt vmcnt(0)" ::: "memory"); }
        __builtin_amdgcn_s_barrier();
    }

#undef STAGE_A
#undef STAGE_B
#undef LDA
#undef LDB

    // ---- epilogue: per-lane LSTM combine (j == gate) ----
    const int col = n0 + wc * 16 + l16;
    const float vbi = pbi[col];
    const float vbf = pbf[col];
    const float vbo = pbo[col];
    const float vbg = pbg[col];
    const size_t HB = (size_t)B_DIM * H_DIM;
#pragma unroll
    for (int i = 0; i < 8; ++i) {
        const int fb  = (i < 4) ? (wr * 64 + i * 16) : (128 + wr * 64 + (i - 4) * 16);
        const int mb0 = m_base + fb + quad * 4;
#pragma unroll
        for (int r = 0; r < 4; ++r) {
            const size_t m = (size_t)(mb0 + r);
            const float ip = acc[i][0][r] + vbi;
            const float fp = acc[i][1][r] + vbf;
            const float op = acc[i][2][r] + vbo;
            const float gp = acc[i][3][r] + vbg;
            const float ig = 1.f / (1.f + __expf(-ip));
            const float fg = 1.f / (1.f + __expf(-fp));
            const float og = 1.f / (1.f + __expf(-op));
            const float eg = __expf(-2.f * fabsf(gp));
            const float gg = copysignf((1.f - eg) / (1.f + eg), gp);
            const float cin = c[m * H_DIM + col];
            const float ct = fg * cin + ig * gg;
            const float ec = __expf(-2.f * fabsf(ct));
            const float tc = copysignf((1.f - ec) / (1.f + ec), ct);
            out[m * H_DIM + col]      = og * tc;
            out[HB + m * H_DIM + col] = ct;
        }
    }
}

// ---------------- fallback: fused fp32-load path (small ws) ----------------
#define BM 128
#define BNC 32
#define BK 64
#define K_ITERS (C_DIM / BK)

__global__ __launch_bounds__(256, 2)
void lstm_gemm_fused(const float* __restrict__ x, const float* __restrict__ h,
                     const float* __restrict__ Wi, const float* __restrict__ Wf,
                     const float* __restrict__ Wo, const float* __restrict__ Wg,
                     const float* __restrict__ c,
                     const float* __restrict__ pbi, const float* __restrict__ pbf,
                     const float* __restrict__ pbo, const float* __restrict__ pbg,
                     float* __restrict__ out)
{
    __shared__ __hip_bfloat16 As[BM][BK];
    __shared__ __hip_bfloat16 Bs[BM][BK];

    const int tid  = threadIdx.x;
    const int lane = tid & 63;
    const int wave = tid >> 6;
    const int wr   = wave >> 1;
    const int wc   = wave & 1;
    const int quad = lane >> 4;
    const int l16  = lane & 15;

    const int m_base = blockIdx.y * BM;
    const int n0     = blockIdx.x * BNC;

    const int srow = tid >> 1;
    const int scol = (tid & 1) * 32;
    const float* aS[2] = {
        x + (size_t)(m_base + srow) * H_DIM + scol,
        h + (size_t)(m_base + srow) * H_DIM + scol
    };
    const int gate = (srow >> 4) & 3;
    const int grow = n0 + ((srow >> 6) << 4) + (srow & 15);
    const float* Wsel = (gate == 0) ? Wi : (gate == 1) ? Wf : (gate == 2) ? Wo : Wg;
    const float* bS = Wsel + (size_t)grow * C_DIM + scol;

    int aRow[4], bRow[4];
#pragma unroll
    for (int i = 0; i < 4; ++i) aRow[i] = wr * 64 + i * 16 + l16;
#pragma unroll
    for (int j = 0; j < 4; ++j) bRow[j] = wc * 64 + j * 16 + l16;

    f32x4 acc[4][4];
#pragma unroll
    for (int i = 0; i < 4; ++i)
#pragma unroll
        for (int j = 0; j < 4; ++j)
            acc[i][j] = (f32x4){0.f, 0.f, 0.f, 0.f};

    for (int kt = 0; kt < K_ITERS; ++kt) {
        const int hsel = (kt >= (H_DIM / BK));
        const int koff = (kt & ((H_DIM / BK) - 1)) * BK;
        const float* ap = aS[hsel] + koff;
        const float* bp = bS + kt * BK;
        __hip_bfloat16 ta[32], tb[32];
#pragma unroll
        for (int q = 0; q < 8; ++q) {
            f32x4 a = *(const f32x4*)(ap + q * 4);
            f32x4 b = *(const f32x4*)(bp + q * 4);
            ta[q*4+0]=__float2bfloat16(a[0]); ta[q*4+1]=__float2bfloat16(a[1]);
            ta[q*4+2]=__float2bfloat16(a[2]); ta[q*4+3]=__float2bfloat16(a[3]);
            tb[q*4+0]=__float2bfloat16(b[0]); tb[q*4+1]=__float2bfloat16(b[1]);
            tb[q*4+2]=__float2bfloat16(b[2]); tb[q*4+3]=__float2bfloat16(b[3]);
        }
#pragma unroll
        for (int q = 0; q < 4; ++q) {
            const int ch  = (scol / 8) + q;
            const int sl  = ch ^ (srow & 7);
            *(bf16x8*)((char*)&As[0][0] + srow * (BK * 2) + sl * 16) = *(const bf16x8*)&ta[q * 8];
            *(bf16x8*)((char*)&Bs[0][0] + srow * (BK * 2) + sl * 16) = *(const bf16x8*)&tb[q * 8];
        }
        __syncthreads();

#pragma unroll
        for (int s = 0; s < 2; ++s) {
            bf16x8 av[4], bv[4];
#pragma unroll
            for (int i = 0; i < 4; ++i) {
                const int r  = aRow[i];
                const int ch = (s * 4 + quad) ^ (r & 7);
                av[i] = *(const bf16x8*)((const char*)&As[0][0] + r * (BK * 2) + ch * 16);
            }
#pragma unroll
            for (int j = 0; j < 4; ++j) {
                const int r  = bRow[j];
                const int ch = (s * 4 + quad) ^ (r & 7);
                bv[j] = *(const bf16x8*)((const char*)&Bs[0][0] + r * (BK * 2) + ch * 16);
            }
#pragma unroll
            for (int i = 0; i < 4; ++i)
#pragma unroll
                for (int j = 0; j < 4; ++j)
                    acc[i][j] = __builtin_amdgcn_mfma_f32_16x16x32_bf16(
                        av[i], bv[j], acc[i][j], 0, 0, 0);
        }
        __syncthreads();
    }

    const int col = n0 + wc * 16 + l16;
    const float vbi = pbi[col];
    const float vbf = pbf[col];
    const float vbo = pbo[col];
    const float vbg = pbg[col];
    const size_t HB = (size_t)B_DIM * H_DIM;
#pragma unroll
    for (int i = 0; i < 4; ++i) {
        const int mb = m_base + wr * 64 + i * 16 + quad * 4;
#pragma unroll
        for (int r = 0; r < 4; ++r) {
            const size_t m = (size_t)(mb + r);
            const float ip = acc[i][0][r] + vbi;
            const float fp = acc[i][1][r] + vbf;
            const float op = acc[i][2][r] + vbo;
            const float gp = acc[i][3][r] + vbg;
            const float ig = 1.f / (1.f + __expf(-ip));
            const float fg = 1.f / (1.f + __expf(-fp));
            const float og = 1.f / (1.f + __expf(-op));
            const float eg = __expf(-2.f * fabsf(gp));
            const float gg = copysignf((1.f - eg) / (1.f + eg), gp);
            const float cin = c[m * H_DIM + col];
            const float ct = fg * cin + ig * gg;
            const float ec = __expf(-2.f * fabsf(ct));
            const float tc = copysignf((1.f - ec) / (1.f + ec), ct);
            out[m * H_DIM + col]      = og * tc;
            out[HB + m * H_DIM + col] = ct;
        }
    }
}

extern "C" void kernel_launch(void* const* d_in, const int* in_sizes, int n_in,
                              void* d_out, int out_size, void* d_ws, size_t ws_size,
                              hipStream_t stream) {
    const float* x  = (const float*)d_in[0];
    const float* h  = (const float*)d_in[1];
    const float* c  = (const float*)d_in[2];
    const float* Wi = (const float*)d_in[3];
    const float* Wf = (const float*)d_in[4];
    const float* Wo = (const float*)d_in[5];
    const float* Wg = (const float*)d_in[6];
    const float* bi = (const float*)d_in[7];
    const float* bfp= (const float*)d_in[8];
    const float* bo = (const float*)d_in[9];
    const float* bg = (const float*)d_in[10];
    float* out = (float*)d_out;

    if (ws_size >= WS_NEEDED) {
        __hip_bfloat16* wsb = (__hip_bfloat16*)d_ws;
        cvt_kernel<<<2048, 256, 0, stream>>>(x, h, Wi, Wf, Wo, Wg, wsb);
        lstm_gemm_bf16<<<512, 512, 0, stream>>>(
            wsb, wsb + XH_ELEMS, wsb + 2 * (size_t)XH_ELEMS,
            c, bi, bfp, bo, bg, out);
    } else {
        lstm_gemm_fused<<<dim3(H_DIM / BNC, B_DIM / BM), dim3(256), 0, stream>>>(
            x, h, Wi, Wf, Wo, Wg, c, bi, bfp, bo, bg, out);
    }
}

// Round 5
// 306.119 us; speedup vs baseline: 1.0241x; 1.0088x over previous
//
#include <hip/hip_runtime.h>
#include <hip/hip_bf16.h>
#include <stdint.h>

// LSTM cell, fp32 I/O, GEMM via bf16 MFMA.
//   gates[b, 4H] = [x|h] @ W_stacked^T + b ; per-element LSTM combine, fp32 out.
// B=8192, I=H=1024, C=2048.
//
// Round 10 (= round 9 kernel; round 9 never ran: GPUAcquisitionTimeout):
// Round-8 measured 156us / MfmaUtil 38% -- exactly the "8-phase with
// drain-to-0" signature (m218 V1).  Theory: hipcc's waitcnt pass sees C++
// ds_reads of the same __shared__ object that global_load_lds DMAs into,
// can't disambiguate buffer halves, and inserts s_waitcnt vmcnt(0) before
// each phase's read cluster -- defeating the counted vmcnt(6).
// Fix: fragment reads via inline-asm ds_read_b128 (opaque to the waitcnt
// pass; m214/m203 pattern).  Rule #18 discipline: every consumer phase has
// lgkmcnt(0) + sched_barrier(0) before its MFMAs; phase 4 consumes only
// registers fenced in phases 2/3.  Schedule/ledger/swizzle/epilogue
// unchanged from round 8.

typedef __bf16 bf16x8 __attribute__((ext_vector_type(8)));
typedef __bf16 bf16x4 __attribute__((ext_vector_type(4)));
typedef float f32x4 __attribute__((ext_vector_type(4)));

#define B_DIM 8192
#define H_DIM 1024
#define C_DIM 2048

#define XH_ELEMS (B_DIM * H_DIM)               // 8388608
#define W_ELEMS  (H_DIM * C_DIM)               // 2097152
#define CVT_TOTAL (2 * XH_ELEMS + 4 * W_ELEMS) // 25165824 floats
#define WS_NEEDED ((size_t)CVT_TOTAL * 2)      // bytes of bf16

__device__ __forceinline__ void async_cp16(void* lds_dst, const void* g_src) {
    __builtin_amdgcn_global_load_lds(
        (const __attribute__((address_space(1))) void*)g_src,
        (__attribute__((address_space(3))) void*)lds_dst,
        16, 0, 0);
}

// Opaque LDS read: the waitcnt pass can't see this as an LDS access, so it
// cannot anchor a conservative vmcnt(0) against outstanding global_load_lds.
// Completion is enforced ONLY by our explicit lgkmcnt fences (rule #18).
__device__ __forceinline__ bf16x8 lds_read16(const void* p) {
    bf16x8 r;
    asm volatile("ds_read_b128 %0, %1"
                 : "=v"(r)
                 : "v"((const __attribute__((address_space(3))) void*)p));
    return r;
}

// ---------------- fp32 -> bf16 bulk convert (pass 1) ----------------
__global__ __launch_bounds__(256)
void cvt_kernel(const float* __restrict__ x, const float* __restrict__ h,
                const float* __restrict__ wi, const float* __restrict__ wf,
                const float* __restrict__ wo, const float* __restrict__ wg,
                __hip_bfloat16* __restrict__ dst)
{
    const size_t stride = (size_t)gridDim.x * 256;
    for (size_t t = (size_t)blockIdx.x * 256 + threadIdx.x;
         t < (size_t)(CVT_TOTAL / 8); t += stride) {
        const size_t base = t * 8;
        const float* src;
        size_t off;
        if (base < (size_t)XH_ELEMS)            { src = x; off = base; }
        else if (base < (size_t)2 * XH_ELEMS)   { src = h; off = base - XH_ELEMS; }
        else {
            const size_t wb = base - (size_t)2 * XH_ELEMS;
            const int g = (int)(wb >> 21);          // W_ELEMS = 2^21
            off = wb & (size_t)(W_ELEMS - 1);
            src = (g == 0) ? wi : (g == 1) ? wf : (g == 2) ? wo : wg;
        }
        const f32x4 v0 = *(const f32x4*)(src + off);
        const f32x4 v1 = *(const f32x4*)(src + off + 4);
        __hip_bfloat16 tmp[8];
        tmp[0] = __float2bfloat16(v0[0]); tmp[1] = __float2bfloat16(v0[1]);
        tmp[2] = __float2bfloat16(v0[2]); tmp[3] = __float2bfloat16(v0[3]);
        tmp[4] = __float2bfloat16(v1[0]); tmp[5] = __float2bfloat16(v1[1]);
        tmp[6] = __float2bfloat16(v1[2]); tmp[7] = __float2bfloat16(v1[3]);
        *(bf16x8*)(dst + base) = *(const bf16x8*)tmp;
    }
}

// ---------------- 256x256 8-phase GEMM + LSTM epilogue ----------------
__global__ __launch_bounds__(512, 2)
void lstm_gemm_bf16(const __hip_bfloat16* __restrict__ xb,
                    const __hip_bfloat16* __restrict__ hb,
                    const __hip_bfloat16* __restrict__ Wb,   // [4][H][C]
                    const float* __restrict__ c,
                    const float* __restrict__ pbi, const float* __restrict__ pbf,
                    const float* __restrict__ pbo, const float* __restrict__ pbg,
                    float* __restrict__ out)
{
    // [buf][A=0/B=1][row 0..255][col 0..63] bf16 = 128 KB
    __shared__ __hip_bfloat16 lds[2][2][256][64];
    char* const ldsBase = (char*)&lds[0][0][0][0];

    const int tid  = threadIdx.x;
    const int lane = tid & 63;
    const int wave = tid >> 6;        // 0..7
    const int wr   = wave >> 2;       // 0..1 (M)
    const int wc   = wave & 3;        // 0..3 (N)
    const int quad = lane >> 4;
    const int l16  = lane & 15;

    // XCD-aware swizzle: 512 blocks -> 64-block contiguous chunk per XCD.
    const int bid = (int)blockIdx.x;
    const int swz = (bid & 7) * 64 + (bid >> 3);
    const int m_base = (swz >> 4) * 256;   // 32 m-blocks
    const int n0     = (swz & 15) * 64;    // 16 n-blocks, 64 h-cols each

    // ---- staging offsets: per half-tile, li = a*512+tid in [0,1024) ----
    // row = li>>3 (within 128-row half), dst chunk = li&7,
    // SOURCE chunk = (li&7) ^ (row&7)  (XOR swizzle, involution).
    uint32_t aOff[2][2], bOff[2][2];       // [half][a], element offsets
#pragma unroll
    for (int a = 0; a < 2; ++a) {
        const int li  = a * 512 + tid;
        const int row = li >> 3;           // 0..127
        const int sch = ((li & 7) ^ (row & 7)) * 8;
#pragma unroll
        for (int hh = 0; hh < 2; ++hh) {
            aOff[hh][a] = (uint32_t)(m_base + hh * 128 + row) * H_DIM + (uint32_t)sch;
            // B rows: gate-interleaved so phase jh == B-half and
            // wave wc's j-frag rows map to (gate=j, hcol = n0 + wc*16 + l16).
            const int g   = (hh << 1) | ((row >> 4) & 1);
            const int hco = ((row >> 5) << 4) | (row & 15);
            bOff[hh][a] = (uint32_t)g * (uint32_t)W_ELEMS
                        + (uint32_t)(n0 + hco) * (uint32_t)C_DIM + (uint32_t)sch;
        }
    }
    const uint32_t dstT = (uint32_t)tid * 16u;

#define STAGE_A(pO, hh, srcp, kel) do {                                                        \
    async_cp16(ldsBase + (pO) + (hh) * 16384u + 0u    + dstT, (srcp) + aOff[hh][0] + (kel));   \
    async_cp16(ldsBase + (pO) + (hh) * 16384u + 8192u + dstT, (srcp) + aOff[hh][1] + (kel));   \
} while (0)
#define STAGE_B(pO, hh, kel) do {                                                              \
    async_cp16(ldsBase + (pO) + 32768u + (hh) * 16384u + 0u    + dstT, Wb + bOff[hh][0] + (kel)); \
    async_cp16(ldsBase + (pO) + 32768u + (hh) * 16384u + 8192u + dstT, Wb + bOff[hh][1] + (kel)); \
} while (0)

    // ---- fragment read bases (swizzled chunk = (s*4+quad)^(row&7), row&7 == l16&7) ----
    const uint32_t cb    = (uint32_t)((quad ^ (l16 & 7)) * 16);
    const uint32_t aBase = (uint32_t)(wr * 64 + l16) * 128u + cb;            // A region
    const uint32_t bBase = 32768u + (uint32_t)(wc * 32 + l16) * 128u + cb;   // B region

#define LDA(dstv, pO, ihh, ii, ss) \
    dstv = lds_read16(ldsBase + (pO) + ((aBase + (ihh) * 16384u + (ii) * 2048u) ^ ((uint32_t)(ss) << 6)))
#define LDB(dstv, pO, jj, ss) \
    dstv = lds_read16(ldsBase + (pO) + ((bBase + (((jj) >> 1)) * 16384u + ((jj) & 1) * 2048u) ^ ((uint32_t)(ss) << 6)))

    f32x4 acc[8][4];
#pragma unroll
    for (int i = 0; i < 8; ++i)
#pragma unroll
        for (int j = 0; j < 4; ++j)
            acc[i][j] = (f32x4){0.f, 0.f, 0.f, 0.f};

    // ---- prologue: tile0 {A0,B0,B1,A1}, tile1 {A0,B0,B1}; tile1's A1 comes
    //      from tile0's phase 1.  vmcnt(6) leaves the 3 newest halves in flight.
    STAGE_A(0u, 0, xb, 0u);
    STAGE_B(0u, 0, 0u);
    STAGE_B(0u, 1, 0u);
    STAGE_A(0u, 1, xb, 0u);
    STAGE_A(65536u, 0, xb, 64u);
    STAGE_B(65536u, 0, 64u);
    STAGE_B(65536u, 1, 64u);
    asm volatile("s_waitcnt vmcnt(6)" ::: "memory");
    __builtin_amdgcn_s_barrier();

    bf16x8 av[4][2], bv0[2][2], bv1[2][2];

    for (int u = 0; u < 32; ++u) {
        const uint32_t pO = (uint32_t)(u & 1) * 65536u;   // tile u's buffer
        const uint32_t qO = pO ^ 65536u;                  // tile u+1's buffer
        const __hip_bfloat16* aS1 = (u + 1 < 16) ? xb : hb;
        const uint32_t ak1 = (uint32_t)((u + 1) & 15) * 64u;
        const __hip_bfloat16* aS2 = (u + 2 < 16) ? xb : hb;
        const uint32_t ak2 = (uint32_t)((u + 2) & 15) * 64u;
        const uint32_t bk2 = (uint32_t)(u + 2) * 64u;

        // ---------- phase 1: quadrant A0 x B0 ; stage A1 of tile u+1 ----------
#pragma unroll
        for (int i = 0; i < 4; ++i) { LDA(av[i][0], pO, 0, i, 0); LDA(av[i][1], pO, 0, i, 1); }
#pragma unroll
        for (int j = 0; j < 2; ++j) { LDB(bv0[j][0], pO, j, 0); LDB(bv0[j][1], pO, j, 1); }
        if (u < 31) STAGE_A(qO, 1, aS1, ak1);
        asm volatile("s_waitcnt lgkmcnt(8)");   // partial drain of the 12 reads
        __builtin_amdgcn_s_barrier();
        asm volatile("s_waitcnt lgkmcnt(0)" ::: "memory");
        __builtin_amdgcn_sched_barrier(0);
        __builtin_amdgcn_s_setprio(1);
#pragma unroll
        for (int i = 0; i < 4; ++i)
#pragma unroll
            for (int j = 0; j < 2; ++j) {
                acc[i][j] = __builtin_amdgcn_mfma_f32_16x16x32_bf16(av[i][0], bv0[j][0], acc[i][j], 0, 0, 0);
                acc[i][j] = __builtin_amdgcn_mfma_f32_16x16x32_bf16(av[i][1], bv0[j][1], acc[i][j], 0, 0, 0);
            }
        __builtin_amdgcn_s_setprio(0);
        __builtin_amdgcn_s_barrier();

        // ---------- phase 2: A0 x B1 ; stage A0 of tile u+2 (A0 region idle since P1) ----------
#pragma unroll
        for (int j = 0; j < 2; ++j) { LDB(bv1[j][0], pO, j + 2, 0); LDB(bv1[j][1], pO, j + 2, 1); }
        if (u < 30) STAGE_A(pO, 0, aS2, ak2);
        __builtin_amdgcn_s_barrier();
        asm volatile("s_waitcnt lgkmcnt(0)" ::: "memory");
        __builtin_amdgcn_sched_barrier(0);
        __builtin_amdgcn_s_setprio(1);
#pragma unroll
        for (int i = 0; i < 4; ++i)
#pragma unroll
            for (int j = 0; j < 2; ++j) {
                acc[i][j + 2] = __builtin_amdgcn_mfma_f32_16x16x32_bf16(av[i][0], bv1[j][0], acc[i][j + 2], 0, 0, 0);
                acc[i][j + 2] = __builtin_amdgcn_mfma_f32_16x16x32_bf16(av[i][1], bv1[j][1], acc[i][j + 2], 0, 0, 0);
            }
        __builtin_amdgcn_s_setprio(0);
        __builtin_amdgcn_s_barrier();

        // ---------- phase 3: A1 x B0 ; stage B0 of tile u+2 (B0 region idle since P1) ----------
#pragma unroll
        for (int i = 0; i < 4; ++i) { LDA(av[i][0], pO, 1, i, 0); LDA(av[i][1], pO, 1, i, 1); }
        if (u < 30) STAGE_B(pO, 0, bk2);
        __builtin_amdgcn_s_barrier();
        asm volatile("s_waitcnt lgkmcnt(0)" ::: "memory");
        __builtin_amdgcn_sched_barrier(0);
        __builtin_amdgcn_s_setprio(1);
#pragma unroll
        for (int i = 0; i < 4; ++i)
#pragma unroll
            for (int j = 0; j < 2; ++j) {
                acc[i + 4][j] = __builtin_amdgcn_mfma_f32_16x16x32_bf16(av[i][0], bv0[j][0], acc[i + 4][j], 0, 0, 0);
                acc[i + 4][j] = __builtin_amdgcn_mfma_f32_16x16x32_bf16(av[i][1], bv0[j][1], acc[i + 4][j], 0, 0, 0);
            }
        __builtin_amdgcn_s_setprio(0);
        __builtin_amdgcn_s_barrier();

        // ---------- phase 4: A1 x B1 ; stage B1 of tile u+2 (B1 region idle since P2) ----------
        if (u < 30) STAGE_B(pO, 1, bk2);
        __builtin_amdgcn_s_barrier();
        __builtin_amdgcn_s_setprio(1);
#pragma unroll
        for (int i = 0; i < 4; ++i)
#pragma unroll
            for (int j = 0; j < 2; ++j) {
                acc[i + 4][j + 2] = __builtin_amdgcn_mfma_f32_16x16x32_bf16(av[i][0], bv1[j][0], acc[i + 4][j + 2], 0, 0, 0);
                acc[i + 4][j + 2] = __builtin_amdgcn_mfma_f32_16x16x32_bf16(av[i][1], bv1[j][1], acc[i + 4][j + 2], 0, 0, 0);
            }
        __builtin_amdgcn_s_setprio(0);
        // Once-per-K-tile counted wait: tile u+1 fully landed, newest 3 halves
        // (tile u+2) stay in flight.  Epilogue tiles drain (u==30 -> 0).
        if (u < 30)       { asm volatile("s_waitcnt vmcnt(6)" ::: "memory"); }
        else if (u == 30) { asm volatile("s_waitcnt vmcnt(0)" ::: "memory"); }
        __builtin_amdgcn_s_barrier();
    }

#undef STAGE_A
#undef STAGE_B
#undef LDA
#undef LDB

    // ---- epilogue: per-lane LSTM combine (j == gate) ----
    const int col = n0 + wc * 16 + l16;
    const float vbi = pbi[col];
    const float vbf = pbf[col];
    const float vbo = pbo[col];
    const float vbg = pbg[col];
    const size_t HB = (size_t)B_DIM * H_DIM;
#pragma unroll
    for (int i = 0; i < 8; ++i) {
        const int fb  = (i < 4) ? (wr * 64 + i * 16) : (128 + wr * 64 + (i - 4) * 16);
        const int mb0 = m_base + fb + quad * 4;
#pragma unroll
        for (int r = 0; r < 4; ++r) {
            const size_t m = (size_t)(mb0 + r);
            const float ip = acc[i][0][r] + vbi;
            const float fp = acc[i][1][r] + vbf;
            const float op = acc[i][2][r] + vbo;
            const float gp = acc[i][3][r] + vbg;
            const float ig = 1.f / (1.f + __expf(-ip));
            const float fg = 1.f / (1.f + __expf(-fp));
            const float og = 1.f / (1.f + __expf(-op));
            const float eg = __expf(-2.f * fabsf(gp));
            const float gg = copysignf((1.f - eg) / (1.f + eg), gp);
            const float cin = c[m * H_DIM + col];
            const float ct = fg * cin + ig * gg;
            const float ec = __expf(-2.f * fabsf(ct));
            const float tc = copysignf((1.f - ec) / (1.f + ec), ct);
            out[m * H_DIM + col]      = og * tc;
            out[HB + m * H_DIM + col] = ct;
        }
    }
}

// ---------------- fallback: fused fp32-load path (small ws) ----------------
#define BM 128
#define BNC 32
#define BK 64
#define K_ITERS (C_DIM / BK)

__global__ __launch_bounds__(256, 2)
void lstm_gemm_fused(const float* __restrict__ x, const float* __restrict__ h,
                     const float* __restrict__ Wi, const float* __restrict__ Wf,
                     const float* __restrict__ Wo, const float* __restrict__ Wg,
                     const float* __restrict__ c,
                     const float* __restrict__ pbi, const float* __restrict__ pbf,
                     const float* __restrict__ pbo, const float* __restrict__ pbg,
                     float* __restrict__ out)
{
    __shared__ __hip_bfloat16 As[BM][BK];
    __shared__ __hip_bfloat16 Bs[BM][BK];

    const int tid  = threadIdx.x;
    const int lane = tid & 63;
    const int wave = tid >> 6;
    const int wr   = wave >> 1;
    const int wc   = wave & 1;
    const int quad = lane >> 4;
    const int l16  = lane & 15;

    const int m_base = blockIdx.y * BM;
    const int n0     = blockIdx.x * BNC;

    const int srow = tid >> 1;
    const int scol = (tid & 1) * 32;
    const float* aS[2] = {
        x + (size_t)(m_base + srow) * H_DIM + scol,
        h + (size_t)(m_base + srow) * H_DIM + scol
    };
    const int gate = (srow >> 4) & 3;
    const int grow = n0 + ((srow >> 6) << 4) + (srow & 15);
    const float* Wsel = (gate == 0) ? Wi : (gate == 1) ? Wf : (gate == 2) ? Wo : Wg;
    const float* bS = Wsel + (size_t)grow * C_DIM + scol;

    int aRow[4], bRow[4];
#pragma unroll
    for (int i = 0; i < 4; ++i) aRow[i] = wr * 64 + i * 16 + l16;
#pragma unroll
    for (int j = 0; j < 4; ++j) bRow[j] = wc * 64 + j * 16 + l16;

    f32x4 acc[4][4];
#pragma unroll
    for (int i = 0; i < 4; ++i)
#pragma unroll
        for (int j = 0; j < 4; ++j)
            acc[i][j] = (f32x4){0.f, 0.f, 0.f, 0.f};

    for (int kt = 0; kt < K_ITERS; ++kt) {
        const int hsel = (kt >= (H_DIM / BK));
        const int koff = (kt & ((H_DIM / BK) - 1)) * BK;
        const float* ap = aS[hsel] + koff;
        const float* bp = bS + kt * BK;
        __hip_bfloat16 ta[32], tb[32];
#pragma unroll
        for (int q = 0; q < 8; ++q) {
            f32x4 a = *(const f32x4*)(ap + q * 4);
            f32x4 b = *(const f32x4*)(bp + q * 4);
            ta[q*4+0]=__float2bfloat16(a[0]); ta[q*4+1]=__float2bfloat16(a[1]);
            ta[q*4+2]=__float2bfloat16(a[2]); ta[q*4+3]=__float2bfloat16(a[3]);
            tb[q*4+0]=__float2bfloat16(b[0]); tb[q*4+1]=__float2bfloat16(b[1]);
            tb[q*4+2]=__float2bfloat16(b[2]); tb[q*4+3]=__float2bfloat16(b[3]);
        }
#pragma unroll
        for (int q = 0; q < 4; ++q) {
            const int ch  = (scol / 8) + q;
            const int sl  = ch ^ (srow & 7);
            *(bf16x8*)((char*)&As[0][0] + srow * (BK * 2) + sl * 16) = *(const bf16x8*)&ta[q * 8];
            *(bf16x8*)((char*)&Bs[0][0] + srow * (BK * 2) + sl * 16) = *(const bf16x8*)&tb[q * 8];
        }
        __syncthreads();

#pragma unroll
        for (int s = 0; s < 2; ++s) {
            bf16x8 av[4], bv[4];
#pragma unroll
            for (int i = 0; i < 4; ++i) {
                const int r  = aRow[i];
                const int ch = (s * 4 + quad) ^ (r & 7);
                av[i] = *(const bf16x8*)((const char*)&As[0][0] + r * (BK * 2) + ch * 16);
            }
#pragma unroll
            for (int j = 0; j < 4; ++j) {
                const int r  = bRow[j];
                const int ch = (s * 4 + quad) ^ (r & 7);
                bv[j] = *(const bf16x8*)((const char*)&Bs[0][0] + r * (BK * 2) + ch * 16);
            }
#pragma unroll
            for (int i = 0; i < 4; ++i)
#pragma unroll
                for (int j = 0; j < 4; ++j)
                    acc[i][j] = __builtin_amdgcn_mfma_f32_16x16x32_bf16(
                        av[i], bv[j], acc[i][j], 0, 0, 0);
        }
        __syncthreads();
    }

    const int col = n0 + wc * 16 + l16;
    const float vbi = pbi[col];
    const float vbf = pbf[col];
    const float vbo = pbo[col];
    const float vbg = pbg[col];
    const size_t HB = (size_t)B_DIM * H_DIM;
#pragma unroll
    for (int i = 0; i < 4; ++i) {
        const int mb = m_base + wr * 64 + i * 16 + quad * 4;
#pragma unroll
        for (int r = 0; r < 4; ++r) {
            const size_t m = (size_t)(mb + r);
            const float ip = acc[i][0][r] + vbi;
            const float fp = acc[i][1][r] + vbf;
            const float op = acc[i][2][r] + vbo;
            const float gp = acc[i][3][r] + vbg;
            const float ig = 1.f / (1.f + __expf(-ip));
            const float fg = 1.f / (1.f + __expf(-fp));
            const float og = 1.f / (1.f + __expf(-op));
            const float eg = __expf(-2.f * fabsf(gp));
            const float gg = copysignf((1.f - eg) / (1.f + eg), gp);
            const float cin = c[m * H_DIM + col];
            const float ct = fg * cin + ig * gg;
            const float ec = __expf(-2.f * fabsf(ct));
            const float tc = copysignf((1.f - ec) / (1.f + ec), ct);
            out[m * H_DIM + col]      = og * tc;
            out[HB + m * H_DIM + col] = ct;
        }
    }
}

extern "C" void kernel_launch(void* const* d_in, const int* in_sizes, int n_in,
                              void* d_out, int out_size, void* d_ws, size_t ws_size,
                              hipStream_t stream) {
    const float* x  = (const float*)d_in[0];
    const float* h  = (const float*)d_in[1];
    const float* c  = (const float*)d_in[2];
    const float* Wi = (const float*)d_in[3];
    const float* Wf = (const float*)d_in[4];
    const float* Wo = (const float*)d_in[5];
    const float* Wg = (const float*)d_in[6];
    const float* bi = (const float*)d_in[7];
    const float* bfp= (const float*)d_in[8];
    const float* bo = (const float*)d_in[9];
    const float* bg = (const float*)d_in[10];
    float* out = (float*)d_out;

    if (ws_size >= WS_NEEDED) {
        __hip_bfloat16* wsb = (__hip_bfloat16*)d_ws;
        cvt_kernel<<<2048, 256, 0, stream>>>(x, h, Wi, Wf, Wo, Wg, wsb);
        lstm_gemm_bf16<<<512, 512, 0, stream>>>(
            wsb, wsb + XH_ELEMS, wsb + 2 * (size_t)XH_ELEMS,
            c, bi, bfp, bo, bg, out);
    } else {
        lstm_gemm_fused<<<dim3(H_DIM / BNC, B_DIM / BM), dim3(256), 0, stream>>>(
            x, h, Wi, Wf, Wo, Wg, c, bi, bfp, bo, bg, out);
    }
}